// Round 3
// 3023.247 us; speedup vs baseline: 1.0363x; 1.0363x over previous
//
#include <hip/hip_runtime.h>

#define Bx 64
#define Tx 512
#define Dx 1024
#define Ux 1024
#define Mx (Bx*Tx)   // 32768

typedef __attribute__((ext_vector_type(8))) short short8;
typedef __attribute__((ext_vector_type(4))) float f32x4;
typedef __attribute__((ext_vector_type(4))) unsigned int u32x4;

static __device__ __forceinline__ unsigned short f2bf(float f){
  unsigned int u = __builtin_bit_cast(unsigned int, f);
  u = (u + 0x7FFFu + ((u >> 16) & 1u)) >> 16;
  return (unsigned short)u;
}
static __device__ __forceinline__ float bf2f(unsigned short s){
  unsigned int u = ((unsigned int)s) << 16;
  return __builtin_bit_cast(float, u);
}

// ---------------------------------------------------------------------------
// prep: W1T[n][k] = bf16(W1[k][n]); W2T[n][k] = bf16(W2[k][n])  (1024x1024)
// ---------------------------------------------------------------------------
__global__ __launch_bounds__(256) void prep_kernel(
    const float* __restrict__ W1, const float* __restrict__ W2,
    unsigned short* __restrict__ W1T, unsigned short* __restrict__ W2T)
{
  __shared__ unsigned short tile[64][72];
  const float* src = blockIdx.y ? W2 : W1;
  unsigned short* dst = blockIdx.y ? W2T : W1T;
  const int bi = blockIdx.x >> 4;
  const int bj = blockIdx.x & 15;
  const int r  = threadIdx.x >> 2;
  const int c0 = (threadIdx.x & 3) * 16;
  for (int i = 0; i < 4; ++i){
    float4 v = *(const float4*)&src[(size_t)(bi*64 + r)*1024 + bj*64 + c0 + i*4];
    tile[r][c0+i*4+0] = f2bf(v.x);
    tile[r][c0+i*4+1] = f2bf(v.y);
    tile[r][c0+i*4+2] = f2bf(v.z);
    tile[r][c0+i*4+3] = f2bf(v.w);
  }
  __syncthreads();
  unsigned short tmp[16];
  #pragma unroll
  for (int i = 0; i < 16; ++i) tmp[i] = tile[c0+i][r];
  unsigned int w[8];
  #pragma unroll
  for (int i = 0; i < 8; ++i) w[i] = (unsigned int)tmp[2*i] | ((unsigned int)tmp[2*i+1] << 16);
  unsigned short* o = &dst[(size_t)(bj*64 + r)*1024 + bi*64 + c0];
  *(uint4*)o       = make_uint4(w[0],w[1],w[2],w[3]);
  *(uint4*)(o + 8) = make_uint4(w[4],w[5],w[6],w[7]);
}

// ---------------------------------------------------------------------------
// gemm_h: h[m][n] = tanh( X[m][:] @ W1[:][n] + b1[n] ), fp32 out. (unchanged)
// ---------------------------------------------------------------------------
__global__ __launch_bounds__(256) void gemm_h(
    const float* __restrict__ X, const unsigned short* __restrict__ W1T,
    const float* __restrict__ b1, float* __restrict__ h)
{
  __shared__ unsigned short Ah[128][40];
  __shared__ unsigned short Al[128][40];
  __shared__ unsigned short Bt[128][40];
  const int m0 = blockIdx.x * 128, n0 = blockIdx.y * 128;
  const int tid = threadIdx.x;
  const int lane = tid & 63, wave = tid >> 6;
  const int mq = (wave >> 1) * 64, nq = (wave & 1) * 64;
  const int rs = tid >> 1, ks = (tid & 1) * 16;
  f32x4 z = {0.f, 0.f, 0.f, 0.f};
  f32x4 acc[4][4];
  for (int i = 0; i < 4; ++i) for (int j = 0; j < 4; ++j) acc[i][j] = z;

  const int mm = lane & 15, g = lane >> 4;
  for (int kc = 0; kc < 32; ++kc){
    const int kg = kc * 32;
    {
      const float* xp = &X[(size_t)(m0 + rs)*1024 + kg + ks];
      #pragma unroll
      for (int i = 0; i < 4; ++i){
        float4 v = *(const float4*)(xp + i*4);
        unsigned short h0=f2bf(v.x), h1=f2bf(v.y), h2=f2bf(v.z), h3=f2bf(v.w);
        unsigned short l0=f2bf(v.x-bf2f(h0)), l1=f2bf(v.y-bf2f(h1));
        unsigned short l2=f2bf(v.z-bf2f(h2)), l3=f2bf(v.w-bf2f(h3));
        *(uint2*)&Ah[rs][ks+i*4] = make_uint2((unsigned)h0|((unsigned)h1<<16), (unsigned)h2|((unsigned)h3<<16));
        *(uint2*)&Al[rs][ks+i*4] = make_uint2((unsigned)l0|((unsigned)l1<<16), (unsigned)l2|((unsigned)l3<<16));
      }
      const unsigned short* wp = &W1T[(size_t)(n0 + rs)*1024 + kg + ks];
      *(uint4*)&Bt[rs][ks]     = *(const uint4*)wp;
      *(uint4*)&Bt[rs][ks + 8] = *(const uint4*)(wp + 8);
    }
    __syncthreads();
    short8 bf[4], ah[4], al[4];
    #pragma unroll
    for (int j = 0; j < 4; ++j) bf[j] = *(const short8*)&Bt[nq + j*16 + mm][g*8];
    #pragma unroll
    for (int i = 0; i < 4; ++i){
      ah[i] = *(const short8*)&Ah[mq + i*16 + mm][g*8];
      al[i] = *(const short8*)&Al[mq + i*16 + mm][g*8];
    }
    #pragma unroll
    for (int i = 0; i < 4; ++i)
      #pragma unroll
      for (int j = 0; j < 4; ++j){
        acc[i][j] = __builtin_amdgcn_mfma_f32_16x16x32_bf16(ah[i], bf[j], acc[i][j], 0, 0, 0);
        acc[i][j] = __builtin_amdgcn_mfma_f32_16x16x32_bf16(al[i], bf[j], acc[i][j], 0, 0, 0);
      }
    __syncthreads();
  }
  for (int i = 0; i < 4; ++i){
    const int mbase = m0 + mq + i*16 + g*4;
    for (int j = 0; j < 4; ++j){
      const int n = n0 + nq + j*16 + mm;
      const float bias = b1[n];
      #pragma unroll
      for (int r = 0; r < 4; ++r)
        h[(size_t)(mbase + r)*1024 + n] = tanhf(acc[i][j][r] + bias);
    }
  }
}

// ---------------------------------------------------------------------------
// rnn_scan v10: v7's proven MALL protocol, byte-for-byte, with ONE change:
//  staging issues all 16 dwordx4 loads in a single asm block with a single
//  s_waitcnt vmcnt(0) (v7 used two serialized 8-load batches, i.e. two MALL
//  round trips per step). XCD-local experiments (v8/v9) are abandoned: sc0
//  bits are scope encodings (stale L1 reads), buffer_inv path failed at the
//  harness level. Correctness protocol is exactly v7:
//  - producer: 4B relaxed agent atomic stores (state), vmcnt(0) drain,
//    per-wave atomic flag.
//  - consumer: atomic-load flag poll, then sc0 sc1 (system-scope) dwordx4
//    staging reads from MALL.
// 256 WGs = 32 col-parts x 8 batch-groups, 128 threads.
// ---------------------------------------------------------------------------

// 16 system-scope loads, ONE drain (single MALL round trip).
#define STAGE16(DD, SP, TID) do { \
      const unsigned int base = (unsigned int)(TID) * 16u; \
      asm volatile( \
        "global_load_dwordx4 %0,  %16, %32 sc0 sc1\n\t" \
        "global_load_dwordx4 %1,  %17, %32 sc0 sc1\n\t" \
        "global_load_dwordx4 %2,  %18, %32 sc0 sc1\n\t" \
        "global_load_dwordx4 %3,  %19, %32 sc0 sc1\n\t" \
        "global_load_dwordx4 %4,  %20, %32 sc0 sc1\n\t" \
        "global_load_dwordx4 %5,  %21, %32 sc0 sc1\n\t" \
        "global_load_dwordx4 %6,  %22, %32 sc0 sc1\n\t" \
        "global_load_dwordx4 %7,  %23, %32 sc0 sc1\n\t" \
        "global_load_dwordx4 %8,  %24, %32 sc0 sc1\n\t" \
        "global_load_dwordx4 %9,  %25, %32 sc0 sc1\n\t" \
        "global_load_dwordx4 %10, %26, %32 sc0 sc1\n\t" \
        "global_load_dwordx4 %11, %27, %32 sc0 sc1\n\t" \
        "global_load_dwordx4 %12, %28, %32 sc0 sc1\n\t" \
        "global_load_dwordx4 %13, %29, %32 sc0 sc1\n\t" \
        "global_load_dwordx4 %14, %30, %32 sc0 sc1\n\t" \
        "global_load_dwordx4 %15, %31, %32 sc0 sc1\n\t" \
        "s_waitcnt vmcnt(0)" \
        : "=&v"(DD[0]), "=&v"(DD[1]), "=&v"(DD[2]), "=&v"(DD[3]), \
          "=&v"(DD[4]), "=&v"(DD[5]), "=&v"(DD[6]), "=&v"(DD[7]), \
          "=&v"(DD[8]), "=&v"(DD[9]), "=&v"(DD[10]),"=&v"(DD[11]), \
          "=&v"(DD[12]),"=&v"(DD[13]),"=&v"(DD[14]),"=&v"(DD[15]) \
        : "v"(base),        "v"(base+ 2048u), "v"(base+ 4096u), "v"(base+ 6144u), \
          "v"(base+ 8192u), "v"(base+10240u), "v"(base+12288u), "v"(base+14336u), \
          "v"(base+16384u), "v"(base+18432u), "v"(base+20480u), "v"(base+22528u), \
          "v"(base+24576u), "v"(base+26624u), "v"(base+28672u), "v"(base+30720u), \
          "s"(SP) \
        : "memory"); \
    } while(0)

__global__ __launch_bounds__(128) void rnn_scan(
    const unsigned short* __restrict__ W2T, const float* __restrict__ hbuf,
    const float* __restrict__ b2,
    unsigned int* sP0, unsigned int* sP1,
    unsigned int* flags, unsigned short* __restrict__ feat)
{
  __shared__ unsigned short Wt[32][1024];   // 64 KB, XOR-swizzled
  __shared__ unsigned short Shi[8][1040];
  __shared__ unsigned short Slo[8][1040];
  const int tid = threadIdx.x, lane = tid & 63, wv = tid >> 6;
  const int p = (int)blockIdx.x & 31, q = (int)blockIdx.x >> 5;
  const int n0 = p * 32, b0 = q * 8;

  // ---- load W2T slice [n0..n0+32)[0..1024), chunk-XOR swizzle -------------
  for (int i = 0; i < 32; ++i){
    int f = i * 128 + tid;
    int nn = f >> 7, c = f & 127;
    uint4 v = *(const uint4*)&W2T[(size_t)(n0 + nn)*1024 + c*8];
    int cs = c ^ (nn & 7);
    *(uint4*)&Wt[nn][cs*8] = v;
  }
  __syncthreads();

  const int mm = lane & 15, g = lane >> 4;
  const int r8 = lane & 7;
  const int nloc = wv*16 + mm;
  const int wid = p*2 + wv;                 // producer-wave id in group (0..63)
  const int n = n0 + nloc;
  const bool act = (g < 2);
  const int brow = b0 + g*4;
  unsigned int* gflag = flags + (size_t)q * 512 * 64;
  const float bias = b2[n];

  #pragma unroll 1
  for (int t = 0; t < 512; ++t){
    const unsigned int* rsg = (t & 1) ? sP1 : sP0;
    unsigned int* wsb = (t & 1) ? sP0 : sP1;

    // prefetch hbuf[t] before the poll
    float hv[4];
    if (act){
      #pragma unroll
      for (int r = 0; r < 4; ++r)
        hv[r] = hbuf[(size_t)(brow + r)*Tx*Ux + (size_t)t*Ux + n];
    }

    // ---- wait for all 64 producer waves of step t-1 (proven atomic poll) --
    if (t > 0){
      const unsigned int* f = gflag + (size_t)(t-1)*64 + lane;
      int budget = 1 << 22;
      while (true){
        unsigned int v = __hip_atomic_load(f, __ATOMIC_RELAXED, __HIP_MEMORY_SCOPE_AGENT);
        if (__all(v != 0) || --budget == 0) break;
        __builtin_amdgcn_s_sleep(1);
      }
    }

    // ---- stage state slice (8 rows x 1024 packed dwords = 32 KB/WG) -------
    // WG-cooperative, non-atomic dwordx4 system-scope (sc0 sc1) loads.
    // v10: single 16-load batch + one drain (v7 had two serialized batches).
    const unsigned int* sp = rsg + (size_t)b0 * 1024;
    u32x4 dd[16];
    STAGE16(dd, sp, tid);

    // unpack packed dwords -> LDS hi/lo planes
    #pragma unroll
    for (int i = 0; i < 16; ++i){
      const int c = tid + 128*i;
      const int row = c >> 8, col = (c & 255) * 4;
      u32x4 d = dd[i];
      unsigned int h0 = (d.x >> 16) | (d.y & 0xffff0000u);
      unsigned int h1 = (d.z >> 16) | (d.w & 0xffff0000u);
      unsigned int l0 = (d.x & 0xffffu) | (d.y << 16);
      unsigned int l1 = (d.z & 0xffffu) | (d.w << 16);
      *(uint2*)&Shi[row][col] = make_uint2(h0, h1);
      *(uint2*)&Slo[row][col] = make_uint2(l0, l1);
    }
    __syncthreads();   // both waves' plane halves visible
    // WAR safety without a 2nd barrier: staging for t+1 only starts after
    // BOTH waves' flags for t are up (poll), and a wave's flag t is ordered
    // after its MFMA consumed Shi/Slo (acc -> stores -> vmcnt drain -> flag).

    // ---- MFMA: 8x32 tile of state @ W2 slice ------------------------------
    f32x4 a0 = {0,0,0,0}, a1 = {0,0,0,0}, a2 = {0,0,0,0}, a3 = {0,0,0,0};
    #pragma unroll
    for (int ks = 0; ks < 32; ks += 2){
      const int k0 = ks * 32;
      short8 ah0 = *(const short8*)&Shi[r8][k0 + g*8];
      short8 al0 = *(const short8*)&Slo[r8][k0 + g*8];
      short8 ah1 = *(const short8*)&Shi[r8][k0 + 32 + g*8];
      short8 al1 = *(const short8*)&Slo[r8][k0 + 32 + g*8];
      const int c0 = (k0 >> 3) + g, c1 = c0 + 4;
      short8 b0f = *(const short8*)&Wt[nloc][(c0 ^ (nloc & 7))*8];
      short8 b1f = *(const short8*)&Wt[nloc][(c1 ^ (nloc & 7))*8];
      a0 = __builtin_amdgcn_mfma_f32_16x16x32_bf16(ah0, b0f, a0, 0,0,0);
      a1 = __builtin_amdgcn_mfma_f32_16x16x32_bf16(al0, b0f, a1, 0,0,0);
      a2 = __builtin_amdgcn_mfma_f32_16x16x32_bf16(ah1, b1f, a2, 0,0,0);
      a3 = __builtin_amdgcn_mfma_f32_16x16x32_bf16(al1, b1f, a3, 0,0,0);
    }
    f32x4 acc = (a0 + a1) + (a2 + a3);

    // ---- epilogue: rows brow..brow+3 (lanes g<2), col n -------------------
    unsigned int dw[4];
    if (act){
      #pragma unroll
      for (int r = 0; r < 4; ++r){
        const int b = brow + r;
        const float y = hv[r] + tanhf(acc[r] + bias);
        unsigned short yh = f2bf(y);
        unsigned short yl = f2bf(y - bf2f(yh));
        dw[r] = ((unsigned int)yh << 16) | (unsigned int)yl;
        __hip_atomic_store(&wsb[b*1024 + n], dw[r],
                           __ATOMIC_RELAXED, __HIP_MEMORY_SCOPE_AGENT);
      }
    }
    // drain state stores to the coherence point, then publish wave flag
    asm volatile("s_waitcnt vmcnt(0)" ::: "memory");
    if (lane == 0)
      __hip_atomic_store(gflag + (size_t)t*64 + wid, 1u,
                         __ATOMIC_RELAXED, __HIP_MEMORY_SCOPE_AGENT);
    // feat stores AFTER publish: off the critical path
    if (act){
      #pragma unroll
      for (int r = 0; r < 4; ++r)
        feat[(size_t)(brow + r)*Tx*Ux + (size_t)t*Ux + n] = (unsigned short)(dw[r] >> 16);
    }
  }
}

// ---------------------------------------------------------------------------
// proj_out: out[m] = feat[m][:] (bf16) . Wc (fp32) + bc
// ---------------------------------------------------------------------------
__global__ __launch_bounds__(256) void proj_out(
    const unsigned short* __restrict__ feat, const float* __restrict__ Wc,
    const float* __restrict__ bc, float* __restrict__ out)
{
  const int wv = threadIdx.x >> 6, lane = threadIdx.x & 63;
  const int m = blockIdx.x * 4 + wv;
  const unsigned short* fp = &feat[(size_t)m*1024 + lane*16];
  float s = 0.f;
  #pragma unroll
  for (int i = 0; i < 2; ++i){
    uint4 v = *(const uint4*)(fp + i*8);
    float4 w0 = *(const float4*)&Wc[lane*16 + i*8];
    float4 w1 = *(const float4*)&Wc[lane*16 + i*8 + 4];
    unsigned int vv[4] = {v.x, v.y, v.z, v.w};
    s += bf2f((unsigned short)(vv[0] & 0xFFFF))*w0.x + bf2f((unsigned short)(vv[0] >> 16))*w0.y;
    s += bf2f((unsigned short)(vv[1] & 0xFFFF))*w0.z + bf2f((unsigned short)(vv[1] >> 16))*w0.w;
    s += bf2f((unsigned short)(vv[2] & 0xFFFF))*w1.x + bf2f((unsigned short)(vv[2] >> 16))*w1.y;
    s += bf2f((unsigned short)(vv[3] & 0xFFFF))*w1.z + bf2f((unsigned short)(vv[3] >> 16))*w1.w;
  }
  for (int o = 32; o; o >>= 1) s += __shfl_down(s, o);
  if (lane == 0) out[m] = s + bc[0];
}

// ---------------------------------------------------------------------------
extern "C" void kernel_launch(void* const* d_in, const int* in_sizes, int n_in,
                              void* d_out, int out_size, void* d_ws, size_t ws_size,
                              hipStream_t stream)
{
  (void)in_sizes; (void)n_in; (void)out_size; (void)ws_size;
  const float* X  = (const float*)d_in[0];
  const float* W1 = (const float*)d_in[1];
  const float* b1 = (const float*)d_in[2];
  const float* W2 = (const float*)d_in[3];
  const float* b2 = (const float*)d_in[4];
  const float* Wc = (const float*)d_in[5];
  const float* bc = (const float*)d_in[6];
  float* out = (float*)d_out;
  char* ws = (char*)d_ws;

  unsigned short* W1T  = (unsigned short*)(ws + 0);          // 2 MiB
  unsigned short* W2T  = (unsigned short*)(ws + 2097152);    // 2 MiB
  unsigned int*   sP0  = (unsigned int*)  (ws + 4194304);    // 256 KiB packed state
  unsigned int*   sP1  = (unsigned int*)  (ws + 4456448);    // 256 KiB
  unsigned int*   flags= (unsigned int*)  (ws + 4718592);    // 1 MiB (8*512*64*4)
  float* hbuf          = (float*)         (ws + 5767168);    // 128 MiB
  unsigned short* feat = (unsigned short*)(ws + 5767168 + 134217728); // 64 MiB

  // zero state + flags (contiguous 1.5 MiB)
  hipMemsetAsync(sP0, 0, 262144 + 262144 + 1048576, stream);

  prep_kernel<<<dim3(256, 2), 256, 0, stream>>>(W1, W2, W1T, W2T);
  gemm_h<<<dim3(Mx/128, Ux/128), 256, 0, stream>>>(X, W1T, b1, hbuf);

  void* args[] = { (void*)&W2T, (void*)&hbuf, (void*)&b2,
                   (void*)&sP0, (void*)&sP1, (void*)&flags, (void*)&feat };
  hipLaunchCooperativeKernel((void*)rnn_scan, dim3(256), dim3(128), args, 0, stream);

  proj_out<<<Mx/4, 256, 0, stream>>>(feat, Wc, bc, out);
}

// Round 4
// 2839.366 us; speedup vs baseline: 1.1034x; 1.0648x over previous
//
#include <hip/hip_runtime.h>

#define Bx 64
#define Tx 512
#define Dx 1024
#define Ux 1024
#define Mx (Bx*Tx)   // 32768

typedef __attribute__((ext_vector_type(8))) short short8;
typedef __attribute__((ext_vector_type(4))) float f32x4;
typedef __attribute__((ext_vector_type(4))) unsigned int u32x4;

static __device__ __forceinline__ unsigned short f2bf(float f){
  unsigned int u = __builtin_bit_cast(unsigned int, f);
  u = (u + 0x7FFFu + ((u >> 16) & 1u)) >> 16;
  return (unsigned short)u;
}
static __device__ __forceinline__ float bf2f(unsigned short s){
  unsigned int u = ((unsigned int)s) << 16;
  return __builtin_bit_cast(float, u);
}

// ---------------------------------------------------------------------------
// prep: W1T[n][k] = bf16(W1[k][n]); W2T[n][k] = bf16(W2[k][n])  (1024x1024)
// ---------------------------------------------------------------------------
__global__ __launch_bounds__(256) void prep_kernel(
    const float* __restrict__ W1, const float* __restrict__ W2,
    unsigned short* __restrict__ W1T, unsigned short* __restrict__ W2T)
{
  __shared__ unsigned short tile[64][72];
  const float* src = blockIdx.y ? W2 : W1;
  unsigned short* dst = blockIdx.y ? W2T : W1T;
  const int bi = blockIdx.x >> 4;
  const int bj = blockIdx.x & 15;
  const int r  = threadIdx.x >> 2;
  const int c0 = (threadIdx.x & 3) * 16;
  for (int i = 0; i < 4; ++i){
    float4 v = *(const float4*)&src[(size_t)(bi*64 + r)*1024 + bj*64 + c0 + i*4];
    tile[r][c0+i*4+0] = f2bf(v.x);
    tile[r][c0+i*4+1] = f2bf(v.y);
    tile[r][c0+i*4+2] = f2bf(v.z);
    tile[r][c0+i*4+3] = f2bf(v.w);
  }
  __syncthreads();
  unsigned short tmp[16];
  #pragma unroll
  for (int i = 0; i < 16; ++i) tmp[i] = tile[c0+i][r];
  unsigned int w[8];
  #pragma unroll
  for (int i = 0; i < 8; ++i) w[i] = (unsigned int)tmp[2*i] | ((unsigned int)tmp[2*i+1] << 16);
  unsigned short* o = &dst[(size_t)(bj*64 + r)*1024 + bi*64 + c0];
  *(uint4*)o       = make_uint4(w[0],w[1],w[2],w[3]);
  *(uint4*)(o + 8) = make_uint4(w[4],w[5],w[6],w[7]);
}

// ---------------------------------------------------------------------------
// gemm_h: h[m][n] = tanh( X[m][:] @ W1[:][n] + b1[n] ), fp32 out. (unchanged)
// ---------------------------------------------------------------------------
__global__ __launch_bounds__(256) void gemm_h(
    const float* __restrict__ X, const unsigned short* __restrict__ W1T,
    const float* __restrict__ b1, float* __restrict__ h)
{
  __shared__ unsigned short Ah[128][40];
  __shared__ unsigned short Al[128][40];
  __shared__ unsigned short Bt[128][40];
  const int m0 = blockIdx.x * 128, n0 = blockIdx.y * 128;
  const int tid = threadIdx.x;
  const int lane = tid & 63, wave = tid >> 6;
  const int mq = (wave >> 1) * 64, nq = (wave & 1) * 64;
  const int rs = tid >> 1, ks = (tid & 1) * 16;
  f32x4 z = {0.f, 0.f, 0.f, 0.f};
  f32x4 acc[4][4];
  for (int i = 0; i < 4; ++i) for (int j = 0; j < 4; ++j) acc[i][j] = z;

  const int mm = lane & 15, g = lane >> 4;
  for (int kc = 0; kc < 32; ++kc){
    const int kg = kc * 32;
    {
      const float* xp = &X[(size_t)(m0 + rs)*1024 + kg + ks];
      #pragma unroll
      for (int i = 0; i < 4; ++i){
        float4 v = *(const float4*)(xp + i*4);
        unsigned short h0=f2bf(v.x), h1=f2bf(v.y), h2=f2bf(v.z), h3=f2bf(v.w);
        unsigned short l0=f2bf(v.x-bf2f(h0)), l1=f2bf(v.y-bf2f(h1));
        unsigned short l2=f2bf(v.z-bf2f(h2)), l3=f2bf(v.w-bf2f(h3));
        *(uint2*)&Ah[rs][ks+i*4] = make_uint2((unsigned)h0|((unsigned)h1<<16), (unsigned)h2|((unsigned)h3<<16));
        *(uint2*)&Al[rs][ks+i*4] = make_uint2((unsigned)l0|((unsigned)l1<<16), (unsigned)l2|((unsigned)l3<<16));
      }
      const unsigned short* wp = &W1T[(size_t)(n0 + rs)*1024 + kg + ks];
      *(uint4*)&Bt[rs][ks]     = *(const uint4*)wp;
      *(uint4*)&Bt[rs][ks + 8] = *(const uint4*)(wp + 8);
    }
    __syncthreads();
    short8 bf[4], ah[4], al[4];
    #pragma unroll
    for (int j = 0; j < 4; ++j) bf[j] = *(const short8*)&Bt[nq + j*16 + mm][g*8];
    #pragma unroll
    for (int i = 0; i < 4; ++i){
      ah[i] = *(const short8*)&Ah[mq + i*16 + mm][g*8];
      al[i] = *(const short8*)&Al[mq + i*16 + mm][g*8];
    }
    #pragma unroll
    for (int i = 0; i < 4; ++i)
      #pragma unroll
      for (int j = 0; j < 4; ++j){
        acc[i][j] = __builtin_amdgcn_mfma_f32_16x16x32_bf16(ah[i], bf[j], acc[i][j], 0, 0, 0);
        acc[i][j] = __builtin_amdgcn_mfma_f32_16x16x32_bf16(al[i], bf[j], acc[i][j], 0, 0, 0);
      }
    __syncthreads();
  }
  for (int i = 0; i < 4; ++i){
    const int mbase = m0 + mq + i*16 + g*4;
    for (int j = 0; j < 4; ++j){
      const int n = n0 + nq + j*16 + mm;
      const float bias = b1[n];
      #pragma unroll
      for (int r = 0; r < 4; ++r)
        h[(size_t)(mbase + r)*1024 + n] = tanhf(acc[i][j][r] + bias);
    }
  }
}

// ---------------------------------------------------------------------------
// rnn_scan v11: WG-merge to cut MALL staging redundancy 2x.
//  Theory: step time is dominated by redundant system-scope staging reads --
//  all WGs of a group read the SAME 32 KB slice from MALL (8 MB/step, 524K
//  16B ops). Merge 2 WGs: 16 WGs x 256 threads x 64 cols per group (was
//  32 x 128 x 32). Staging traffic halves; per-thread staging work halves.
//  LDS = Wt 64x1024 (128 KB) + Shi/Slo 8x1024 unpadded (2x16 KB) = exactly
//  160 KiB. Planes are XOR-swizzled in 16B chunks (chunk ^= row) to keep
//  bank spread without padding.
//  Protocol (UNCHANGED, v7-proven): producer 4B relaxed agent atomic stores,
//  vmcnt(0) drain, per-wave atomic flag (64 flags/group = 16 WGs x 4 waves);
//  consumer atomic-load poll, then sc0 sc1 dwordx4 staging from MALL with
//  one drain. Per-wave MFMA work and accumulation order identical ->
//  bit-identical numerics.
// 128 WGs = 16 col-parts x 8 batch-groups, 256 threads.
// ---------------------------------------------------------------------------

// 8 system-scope loads (rows 0..7 of this thread's 4-col strip), ONE drain.
#define STAGE8(DD, SP, TID) do { \
      const unsigned int base = (unsigned int)(TID) * 16u; \
      asm volatile( \
        "global_load_dwordx4 %0, %8,  %16 sc0 sc1\n\t" \
        "global_load_dwordx4 %1, %9,  %16 sc0 sc1\n\t" \
        "global_load_dwordx4 %2, %10, %16 sc0 sc1\n\t" \
        "global_load_dwordx4 %3, %11, %16 sc0 sc1\n\t" \
        "global_load_dwordx4 %4, %12, %16 sc0 sc1\n\t" \
        "global_load_dwordx4 %5, %13, %16 sc0 sc1\n\t" \
        "global_load_dwordx4 %6, %14, %16 sc0 sc1\n\t" \
        "global_load_dwordx4 %7, %15, %16 sc0 sc1\n\t" \
        "s_waitcnt vmcnt(0)" \
        : "=&v"(DD[0]), "=&v"(DD[1]), "=&v"(DD[2]), "=&v"(DD[3]), \
          "=&v"(DD[4]), "=&v"(DD[5]), "=&v"(DD[6]), "=&v"(DD[7]) \
        : "v"(base),         "v"(base+ 4096u), "v"(base+ 8192u), "v"(base+12288u), \
          "v"(base+16384u),  "v"(base+20480u), "v"(base+24576u), "v"(base+28672u), \
          "s"(SP) \
        : "memory"); \
    } while(0)

__global__ __launch_bounds__(256) void rnn_scan(
    const unsigned short* __restrict__ W2T, const float* __restrict__ hbuf,
    const float* __restrict__ b2,
    unsigned int* sP0, unsigned int* sP1,
    unsigned int* flags, unsigned short* __restrict__ feat)
{
  __shared__ unsigned short Wt[64][1024];   // 128 KB, chunk-XOR swizzled
  __shared__ unsigned short Shi[8][1024];   // 16 KB, chunk-XOR swizzled
  __shared__ unsigned short Slo[8][1024];   // 16 KB, chunk-XOR swizzled
  const int tid = threadIdx.x, lane = tid & 63, wv = tid >> 6;
  const int p = (int)blockIdx.x & 15, q = (int)blockIdx.x >> 4;
  const int n0 = p * 64, b0 = q * 8;

  // ---- load W2T slice [n0..n0+64)[0..1024), chunk-XOR swizzle -------------
  for (int i = 0; i < 32; ++i){
    int f = i * 256 + tid;
    int nn = f >> 7, c = f & 127;
    uint4 v = *(const uint4*)&W2T[(size_t)(n0 + nn)*1024 + c*8];
    int cs = c ^ (nn & 7);
    *(uint4*)&Wt[nn][cs*8] = v;
  }
  __syncthreads();

  const int mm = lane & 15, g = lane >> 4;
  const int r8 = lane & 7;
  const int nloc = wv*16 + mm;              // 0..63
  const int wid = p*4 + wv;                 // producer-wave id in group (0..63)
  const int n = n0 + nloc;
  const bool act = (g < 2);
  const int brow = b0 + g*4;
  unsigned int* gflag = flags + (size_t)q * 512 * 64;
  const float bias = b2[n];

  #pragma unroll 1
  for (int t = 0; t < 512; ++t){
    const unsigned int* rsg = (t & 1) ? sP1 : sP0;
    unsigned int* wsb = (t & 1) ? sP0 : sP1;

    // prefetch hbuf[t] before the poll
    float hv[4];
    if (act){
      #pragma unroll
      for (int r = 0; r < 4; ++r)
        hv[r] = hbuf[(size_t)(brow + r)*Tx*Ux + (size_t)t*Ux + n];
    }

    // ---- wait for all 64 producer waves of step t-1 (proven atomic poll) --
    if (t > 0){
      const unsigned int* f = gflag + (size_t)(t-1)*64 + lane;
      int budget = 1 << 22;
      while (true){
        unsigned int v = __hip_atomic_load(f, __ATOMIC_RELAXED, __HIP_MEMORY_SCOPE_AGENT);
        if (__all(v != 0) || --budget == 0) break;
        __builtin_amdgcn_s_sleep(1);
      }
    }

    // ---- stage state slice (8 rows x 1024 packed dwords = 32 KB/WG) -------
    // thread tid: cols 4*tid..4*tid+3 of all 8 rows; 8 dwordx4, one drain.
    const unsigned int* sp = rsg + (size_t)b0 * 1024;
    u32x4 dd[8];
    STAGE8(dd, sp, tid);

    // unpack packed dwords -> swizzled LDS hi/lo planes
    // logical chunk (8 cols) = tid>>1; physical chunk = (tid>>1) ^ row.
    #pragma unroll
    for (int j = 0; j < 8; ++j){
      u32x4 d = dd[j];
      unsigned int h0 = (d.x >> 16) | (d.y & 0xffff0000u);
      unsigned int h1 = (d.z >> 16) | (d.w & 0xffff0000u);
      unsigned int l0 = (d.x & 0xffffu) | (d.y << 16);
      unsigned int l1 = (d.z & 0xffffu) | (d.w << 16);
      const int cp = ((((tid >> 1) ^ j) << 3) + ((tid & 1) << 2));
      *(uint2*)&Shi[j][cp] = make_uint2(h0, h1);
      *(uint2*)&Slo[j][cp] = make_uint2(l0, l1);
    }
    __syncthreads();   // all 4 waves' plane parts visible
    // WAR safety without a 2nd barrier: staging for t+1 only starts after
    // ALL group flags for t are up (poll) -- including this WG's own 4 --
    // and a wave's flag t is ordered after its MFMA consumed Shi/Slo
    // (acc -> stores -> vmcnt drain -> flag).

    // ---- MFMA: 8x64 tile of state @ W2 slice (16 cols per wave) -----------
    f32x4 a0 = {0,0,0,0}, a1 = {0,0,0,0}, a2 = {0,0,0,0}, a3 = {0,0,0,0};
    #pragma unroll
    for (int ks = 0; ks < 32; ks += 2){
      const int k0 = ks * 32;
      const int cc = (k0 >> 3) + g;         // logical 8-col chunk
      short8 ah0 = *(const short8*)&Shi[r8][((cc    ) ^ r8)*8];
      short8 al0 = *(const short8*)&Slo[r8][((cc    ) ^ r8)*8];
      short8 ah1 = *(const short8*)&Shi[r8][((cc + 4) ^ r8)*8];
      short8 al1 = *(const short8*)&Slo[r8][((cc + 4) ^ r8)*8];
      const int c0 = (k0 >> 3) + g, c1 = c0 + 4;
      short8 b0f = *(const short8*)&Wt[nloc][(c0 ^ (nloc & 7))*8];
      short8 b1f = *(const short8*)&Wt[nloc][(c1 ^ (nloc & 7))*8];
      a0 = __builtin_amdgcn_mfma_f32_16x16x32_bf16(ah0, b0f, a0, 0,0,0);
      a1 = __builtin_amdgcn_mfma_f32_16x16x32_bf16(al0, b0f, a1, 0,0,0);
      a2 = __builtin_amdgcn_mfma_f32_16x16x32_bf16(ah1, b1f, a2, 0,0,0);
      a3 = __builtin_amdgcn_mfma_f32_16x16x32_bf16(al1, b1f, a3, 0,0,0);
    }
    f32x4 acc = (a0 + a1) + (a2 + a3);

    // ---- epilogue: rows brow..brow+3 (lanes g<2), col n -------------------
    unsigned int dw[4];
    if (act){
      #pragma unroll
      for (int r = 0; r < 4; ++r){
        const int b = brow + r;
        const float y = hv[r] + tanhf(acc[r] + bias);
        unsigned short yh = f2bf(y);
        unsigned short yl = f2bf(y - bf2f(yh));
        dw[r] = ((unsigned int)yh << 16) | (unsigned int)yl;
        __hip_atomic_store(&wsb[b*1024 + n], dw[r],
                           __ATOMIC_RELAXED, __HIP_MEMORY_SCOPE_AGENT);
      }
    }
    // drain state stores to the coherence point, then publish wave flag
    asm volatile("s_waitcnt vmcnt(0)" ::: "memory");
    if (lane == 0)
      __hip_atomic_store(gflag + (size_t)t*64 + wid, 1u,
                         __ATOMIC_RELAXED, __HIP_MEMORY_SCOPE_AGENT);
    // feat stores AFTER publish: off the critical path
    if (act){
      #pragma unroll
      for (int r = 0; r < 4; ++r)
        feat[(size_t)(brow + r)*Tx*Ux + (size_t)t*Ux + n] = (unsigned short)(dw[r] >> 16);
    }
  }
}

// ---------------------------------------------------------------------------
// proj_out: out[m] = feat[m][:] (bf16) . Wc (fp32) + bc
// ---------------------------------------------------------------------------
__global__ __launch_bounds__(256) void proj_out(
    const unsigned short* __restrict__ feat, const float* __restrict__ Wc,
    const float* __restrict__ bc, float* __restrict__ out)
{
  const int wv = threadIdx.x >> 6, lane = threadIdx.x & 63;
  const int m = blockIdx.x * 4 + wv;
  const unsigned short* fp = &feat[(size_t)m*1024 + lane*16];
  float s = 0.f;
  #pragma unroll
  for (int i = 0; i < 2; ++i){
    uint4 v = *(const uint4*)(fp + i*8);
    float4 w0 = *(const float4*)&Wc[lane*16 + i*8];
    float4 w1 = *(const float4*)&Wc[lane*16 + i*8 + 4];
    unsigned int vv[4] = {v.x, v.y, v.z, v.w};
    s += bf2f((unsigned short)(vv[0] & 0xFFFF))*w0.x + bf2f((unsigned short)(vv[0] >> 16))*w0.y;
    s += bf2f((unsigned short)(vv[1] & 0xFFFF))*w0.z + bf2f((unsigned short)(vv[1] >> 16))*w0.w;
    s += bf2f((unsigned short)(vv[2] & 0xFFFF))*w1.x + bf2f((unsigned short)(vv[2] >> 16))*w1.y;
    s += bf2f((unsigned short)(vv[3] & 0xFFFF))*w1.z + bf2f((unsigned short)(vv[3] >> 16))*w1.w;
  }
  for (int o = 32; o; o >>= 1) s += __shfl_down(s, o);
  if (lane == 0) out[m] = s + bc[0];
}

// ---------------------------------------------------------------------------
extern "C" void kernel_launch(void* const* d_in, const int* in_sizes, int n_in,
                              void* d_out, int out_size, void* d_ws, size_t ws_size,
                              hipStream_t stream)
{
  (void)in_sizes; (void)n_in; (void)out_size; (void)ws_size;
  const float* X  = (const float*)d_in[0];
  const float* W1 = (const float*)d_in[1];
  const float* b1 = (const float*)d_in[2];
  const float* W2 = (const float*)d_in[3];
  const float* b2 = (const float*)d_in[4];
  const float* Wc = (const float*)d_in[5];
  const float* bc = (const float*)d_in[6];
  float* out = (float*)d_out;
  char* ws = (char*)d_ws;

  unsigned short* W1T  = (unsigned short*)(ws + 0);          // 2 MiB
  unsigned short* W2T  = (unsigned short*)(ws + 2097152);    // 2 MiB
  unsigned int*   sP0  = (unsigned int*)  (ws + 4194304);    // 256 KiB packed state
  unsigned int*   sP1  = (unsigned int*)  (ws + 4456448);    // 256 KiB
  unsigned int*   flags= (unsigned int*)  (ws + 4718592);    // 1 MiB (8*512*64*4)
  float* hbuf          = (float*)         (ws + 5767168);    // 128 MiB
  unsigned short* feat = (unsigned short*)(ws + 5767168 + 134217728); // 64 MiB

  // zero state + flags (contiguous 1.5 MiB)
  hipMemsetAsync(sP0, 0, 262144 + 262144 + 1048576, stream);

  prep_kernel<<<dim3(256, 2), 256, 0, stream>>>(W1, W2, W1T, W2T);
  gemm_h<<<dim3(Mx/128, Ux/128), 256, 0, stream>>>(X, W1T, b1, hbuf);

  void* args[] = { (void*)&W2T, (void*)&hbuf, (void*)&b2,
                   (void*)&sP0, (void*)&sP1, (void*)&flags, (void*)&feat };
  hipLaunchCooperativeKernel((void*)rnn_scan, dim3(128), dim3(256), args, 0, stream);

  proj_out<<<Mx/4, 256, 0, stream>>>(feat, Wc, bc, out);
}

// Round 5
// 2383.566 us; speedup vs baseline: 1.3144x; 1.1912x over previous
//
#include <hip/hip_runtime.h>

#define Bx 64
#define Tx 512
#define Dx 1024
#define Ux 1024
#define Mx (Bx*Tx)   // 32768

typedef __attribute__((ext_vector_type(8))) short short8;
typedef __attribute__((ext_vector_type(4))) float f32x4;
typedef __attribute__((ext_vector_type(4))) unsigned int u32x4;

static __device__ __forceinline__ unsigned short f2bf(float f){
  unsigned int u = __builtin_bit_cast(unsigned int, f);
  u = (u + 0x7FFFu + ((u >> 16) & 1u)) >> 16;
  return (unsigned short)u;
}
static __device__ __forceinline__ float bf2f(unsigned short s){
  unsigned int u = ((unsigned int)s) << 16;
  return __builtin_bit_cast(float, u);
}

// ---------------------------------------------------------------------------
// prep: W1T[n][k] = bf16(W1[k][n]); W2T[n][k] = bf16(W2[k][n])  (1024x1024)
// ---------------------------------------------------------------------------
__global__ __launch_bounds__(256) void prep_kernel(
    const float* __restrict__ W1, const float* __restrict__ W2,
    unsigned short* __restrict__ W1T, unsigned short* __restrict__ W2T)
{
  __shared__ unsigned short tile[64][72];
  const float* src = blockIdx.y ? W2 : W1;
  unsigned short* dst = blockIdx.y ? W2T : W1T;
  const int bi = blockIdx.x >> 4;
  const int bj = blockIdx.x & 15;
  const int r  = threadIdx.x >> 2;
  const int c0 = (threadIdx.x & 3) * 16;
  for (int i = 0; i < 4; ++i){
    float4 v = *(const float4*)&src[(size_t)(bi*64 + r)*1024 + bj*64 + c0 + i*4];
    tile[r][c0+i*4+0] = f2bf(v.x);
    tile[r][c0+i*4+1] = f2bf(v.y);
    tile[r][c0+i*4+2] = f2bf(v.z);
    tile[r][c0+i*4+3] = f2bf(v.w);
  }
  __syncthreads();
  unsigned short tmp[16];
  #pragma unroll
  for (int i = 0; i < 16; ++i) tmp[i] = tile[c0+i][r];
  unsigned int w[8];
  #pragma unroll
  for (int i = 0; i < 8; ++i) w[i] = (unsigned int)tmp[2*i] | ((unsigned int)tmp[2*i+1] << 16);
  unsigned short* o = &dst[(size_t)(bj*64 + r)*1024 + bi*64 + c0];
  *(uint4*)o       = make_uint4(w[0],w[1],w[2],w[3]);
  *(uint4*)(o + 8) = make_uint4(w[4],w[5],w[6],w[7]);
}

// ---------------------------------------------------------------------------
// gemm_h: h[m][n] = tanh( X[m][:] @ W1[:][n] + b1[n] ), fp32 out. (unchanged)
// ---------------------------------------------------------------------------
__global__ __launch_bounds__(256) void gemm_h(
    const float* __restrict__ X, const unsigned short* __restrict__ W1T,
    const float* __restrict__ b1, float* __restrict__ h)
{
  __shared__ unsigned short Ah[128][40];
  __shared__ unsigned short Al[128][40];
  __shared__ unsigned short Bt[128][40];
  const int m0 = blockIdx.x * 128, n0 = blockIdx.y * 128;
  const int tid = threadIdx.x;
  const int lane = tid & 63, wave = tid >> 6;
  const int mq = (wave >> 1) * 64, nq = (wave & 1) * 64;
  const int rs = tid >> 1, ks = (tid & 1) * 16;
  f32x4 z = {0.f, 0.f, 0.f, 0.f};
  f32x4 acc[4][4];
  for (int i = 0; i < 4; ++i) for (int j = 0; j < 4; ++j) acc[i][j] = z;

  const int mm = lane & 15, g = lane >> 4;
  for (int kc = 0; kc < 32; ++kc){
    const int kg = kc * 32;
    {
      const float* xp = &X[(size_t)(m0 + rs)*1024 + kg + ks];
      #pragma unroll
      for (int i = 0; i < 4; ++i){
        float4 v = *(const float4*)(xp + i*4);
        unsigned short h0=f2bf(v.x), h1=f2bf(v.y), h2=f2bf(v.z), h3=f2bf(v.w);
        unsigned short l0=f2bf(v.x-bf2f(h0)), l1=f2bf(v.y-bf2f(h1));
        unsigned short l2=f2bf(v.z-bf2f(h2)), l3=f2bf(v.w-bf2f(h3));
        *(uint2*)&Ah[rs][ks+i*4] = make_uint2((unsigned)h0|((unsigned)h1<<16), (unsigned)h2|((unsigned)h3<<16));
        *(uint2*)&Al[rs][ks+i*4] = make_uint2((unsigned)l0|((unsigned)l1<<16), (unsigned)l2|((unsigned)l3<<16));
      }
      const unsigned short* wp = &W1T[(size_t)(n0 + rs)*1024 + kg + ks];
      *(uint4*)&Bt[rs][ks]     = *(const uint4*)wp;
      *(uint4*)&Bt[rs][ks + 8] = *(const uint4*)(wp + 8);
    }
    __syncthreads();
    short8 bf[4], ah[4], al[4];
    #pragma unroll
    for (int j = 0; j < 4; ++j) bf[j] = *(const short8*)&Bt[nq + j*16 + mm][g*8];
    #pragma unroll
    for (int i = 0; i < 4; ++i){
      ah[i] = *(const short8*)&Ah[mq + i*16 + mm][g*8];
      al[i] = *(const short8*)&Al[mq + i*16 + mm][g*8];
    }
    #pragma unroll
    for (int i = 0; i < 4; ++i)
      #pragma unroll
      for (int j = 0; j < 4; ++j){
        acc[i][j] = __builtin_amdgcn_mfma_f32_16x16x32_bf16(ah[i], bf[j], acc[i][j], 0, 0, 0);
        acc[i][j] = __builtin_amdgcn_mfma_f32_16x16x32_bf16(al[i], bf[j], acc[i][j], 0, 0, 0);
      }
    __syncthreads();
  }
  for (int i = 0; i < 4; ++i){
    const int mbase = m0 + mq + i*16 + g*4;
    for (int j = 0; j < 4; ++j){
      const int n = n0 + nq + j*16 + mm;
      const float bias = b1[n];
      #pragma unroll
      for (int r = 0; r < 4; ++r)
        h[(size_t)(mbase + r)*1024 + n] = tanhf(acc[i][j][r] + bias);
    }
  }
}

// ---------------------------------------------------------------------------
// rnn_scan v12: data-as-flag. Collapse the 3 serialized MALL round trips
//  (producer drain -> flag visible -> consumer poll -> staging) into ~1.5:
//  - Each state dword carries a 2-bit tag in the low bits of the lo-plane
//    bf16 (error <= 3*2^-17*|y|, negligible): tag = 1 + (t % 3), never 0.
//    Distinguishes y_t from memset zeros (tag 0) and y_{t-2} (differs mod 3);
//    y_{t-4} is unobservable (same-address coherence order + the producer's
//    own STAGE8 vmcnt(0) at step t-1 drains the t-2 store before t's store).
//  - Producer: v7-proven relaxed agent atomic 4B stores (now tagged), then
//    proceeds IMMEDIATELY: no vmcnt drain, no flag store. The store-ack
//    overlaps the next step's staging latency.
//  - Consumer: retry loop around STAGE8 until all 32 staged dwords carry
//    tag 1+((t-1)%3). Detection = the staging load itself.
//  - Ordering: every WG stages ALL 1024 cols, so passing retry(t+1) proves
//    every producer wave stored y_t, hence finished staging(t) -> the
//    global-buffer WAR ordering of the flag scheme is preserved. The
//    intra-WG LDS WAR (planes) is closed by a second __syncthreads at
//    step end.
// 128 WGs = 16 col-parts x 8 batch-groups, 256 threads.
// ---------------------------------------------------------------------------

// 8 system-scope loads (rows 0..7 of this thread's 4-col strip), ONE drain.
#define STAGE8(DD, SP, TID) do { \
      const unsigned int base = (unsigned int)(TID) * 16u; \
      asm volatile( \
        "global_load_dwordx4 %0, %8,  %16 sc0 sc1\n\t" \
        "global_load_dwordx4 %1, %9,  %16 sc0 sc1\n\t" \
        "global_load_dwordx4 %2, %10, %16 sc0 sc1\n\t" \
        "global_load_dwordx4 %3, %11, %16 sc0 sc1\n\t" \
        "global_load_dwordx4 %4, %12, %16 sc0 sc1\n\t" \
        "global_load_dwordx4 %5, %13, %16 sc0 sc1\n\t" \
        "global_load_dwordx4 %6, %14, %16 sc0 sc1\n\t" \
        "global_load_dwordx4 %7, %15, %16 sc0 sc1\n\t" \
        "s_waitcnt vmcnt(0)" \
        : "=&v"(DD[0]), "=&v"(DD[1]), "=&v"(DD[2]), "=&v"(DD[3]), \
          "=&v"(DD[4]), "=&v"(DD[5]), "=&v"(DD[6]), "=&v"(DD[7]) \
        : "v"(base),         "v"(base+ 4096u), "v"(base+ 8192u), "v"(base+12288u), \
          "v"(base+16384u),  "v"(base+20480u), "v"(base+24576u), "v"(base+28672u), \
          "s"(SP) \
        : "memory"); \
    } while(0)

__global__ __launch_bounds__(256) void rnn_scan(
    const unsigned short* __restrict__ W2T, const float* __restrict__ hbuf,
    const float* __restrict__ b2,
    unsigned int* sP0, unsigned int* sP1,
    unsigned int* flags, unsigned short* __restrict__ feat)
{
  (void)flags;                              // v12: no flags, data-as-flag
  __shared__ unsigned short Wt[64][1024];   // 128 KB, chunk-XOR swizzled
  __shared__ unsigned short Shi[8][1024];   // 16 KB, chunk-XOR swizzled
  __shared__ unsigned short Slo[8][1024];   // 16 KB, chunk-XOR swizzled
  const int tid = threadIdx.x, lane = tid & 63, wv = tid >> 6;
  const int p = (int)blockIdx.x & 15, q = (int)blockIdx.x >> 4;
  const int n0 = p * 64, b0 = q * 8;

  // ---- load W2T slice [n0..n0+64)[0..1024), chunk-XOR swizzle -------------
  for (int i = 0; i < 32; ++i){
    int f = i * 256 + tid;
    int nn = f >> 7, c = f & 127;
    uint4 v = *(const uint4*)&W2T[(size_t)(n0 + nn)*1024 + c*8];
    int cs = c ^ (nn & 7);
    *(uint4*)&Wt[nn][cs*8] = v;
  }
  __syncthreads();

  const int mm = lane & 15, g = lane >> 4;
  const int r8 = lane & 7;
  const int nloc = wv*16 + mm;              // 0..63
  const int n = n0 + nloc;
  const bool act = (g < 2);
  const int brow = b0 + g*4;
  const float bias = b2[n];

  unsigned int tgW = 1u;                    // 1 + (t % 3), incremental
  #pragma unroll 1
  for (int t = 0; t < 512; ++t){
    const unsigned int* rsg = (t & 1) ? sP1 : sP0;
    unsigned int* wsb = (t & 1) ? sP0 : sP1;

    // prefetch hbuf[t] before the staging wait
    float hv[4];
    if (act){
      #pragma unroll
      for (int r = 0; r < 4; ++r)
        hv[r] = hbuf[(size_t)(brow + r)*Tx*Ux + (size_t)t*Ux + n];
    }

    // ---- stage state slice with embedded-tag retry ------------------------
    // thread tid: cols 4*tid..4*tid+3 of all 8 rows; 8 dwordx4, one drain.
    const unsigned int* sp = rsg + (size_t)b0 * 1024;
    u32x4 dd[8];
    if (t > 0){
      const unsigned int tg = (tgW == 1u) ? 3u : (tgW - 1u);  // 1+((t-1)%3)
      int budget = 1 << 14;
      while (true){
        STAGE8(dd, sp, tid);
        bool good = true;
        #pragma unroll
        for (int j = 0; j < 8; ++j){
          good = good && ((dd[j].x & 3u) == tg) && ((dd[j].y & 3u) == tg)
                      && ((dd[j].z & 3u) == tg) && ((dd[j].w & 3u) == tg);
        }
        if (__all(good) || --budget == 0) break;
        __builtin_amdgcn_s_sleep(2);
      }
    } else {
      STAGE8(dd, sp, tid);    // initial zeros, no tag check
    }

    // unpack packed dwords -> swizzled LDS hi/lo planes
    // logical chunk (8 cols) = tid>>1; physical chunk = (tid>>1) ^ row.
    #pragma unroll
    for (int j = 0; j < 8; ++j){
      u32x4 d = dd[j];
      unsigned int h0 = (d.x >> 16) | (d.y & 0xffff0000u);
      unsigned int h1 = (d.z >> 16) | (d.w & 0xffff0000u);
      unsigned int l0 = (d.x & 0xffffu) | (d.y << 16);
      unsigned int l1 = (d.z & 0xffffu) | (d.w << 16);
      const int cp = ((((tid >> 1) ^ j) << 3) + ((tid & 1) << 2));
      *(uint2*)&Shi[j][cp] = make_uint2(h0, h1);
      *(uint2*)&Slo[j][cp] = make_uint2(l0, l1);
    }
    __syncthreads();   // all 4 waves' plane parts visible

    // ---- MFMA: 8x64 tile of state @ W2 slice (16 cols per wave) -----------
    f32x4 a0 = {0,0,0,0}, a1 = {0,0,0,0}, a2 = {0,0,0,0}, a3 = {0,0,0,0};
    #pragma unroll
    for (int ks = 0; ks < 32; ks += 2){
      const int k0 = ks * 32;
      const int cc = (k0 >> 3) + g;         // logical 8-col chunk
      short8 ah0 = *(const short8*)&Shi[r8][((cc    ) ^ r8)*8];
      short8 al0 = *(const short8*)&Slo[r8][((cc    ) ^ r8)*8];
      short8 ah1 = *(const short8*)&Shi[r8][((cc + 4) ^ r8)*8];
      short8 al1 = *(const short8*)&Slo[r8][((cc + 4) ^ r8)*8];
      const int c0 = (k0 >> 3) + g, c1 = c0 + 4;
      short8 b0f = *(const short8*)&Wt[nloc][(c0 ^ (nloc & 7))*8];
      short8 b1f = *(const short8*)&Wt[nloc][(c1 ^ (nloc & 7))*8];
      a0 = __builtin_amdgcn_mfma_f32_16x16x32_bf16(ah0, b0f, a0, 0,0,0);
      a1 = __builtin_amdgcn_mfma_f32_16x16x32_bf16(al0, b0f, a1, 0,0,0);
      a2 = __builtin_amdgcn_mfma_f32_16x16x32_bf16(ah1, b1f, a2, 0,0,0);
      a3 = __builtin_amdgcn_mfma_f32_16x16x32_bf16(al1, b1f, a3, 0,0,0);
    }
    f32x4 acc = (a0 + a1) + (a2 + a3);

    // ---- epilogue: rows brow..brow+3 (lanes g<2), col n -------------------
    // tagged stores; NO drain, NO flag -- ack overlaps next step's staging.
    unsigned int dw[4];
    if (act){
      #pragma unroll
      for (int r = 0; r < 4; ++r){
        const int b = brow + r;
        const float y = hv[r] + tanhf(acc[r] + bias);
        unsigned short yh = f2bf(y);
        unsigned short yl = f2bf(y - bf2f(yh));
        dw[r] = ((unsigned int)yh << 16) | ((unsigned int)(yl & 0xFFFCu)) | tgW;
        __hip_atomic_store(&wsb[b*1024 + n], dw[r],
                           __ATOMIC_RELAXED, __HIP_MEMORY_SCOPE_AGENT);
      }
    }
    // LDS WAR: next step's unpack must not overwrite planes while any wave
    // of this WG is still reading them above.
    __syncthreads();
    // feat stores after the barrier: off the critical path
    if (act){
      #pragma unroll
      for (int r = 0; r < 4; ++r)
        feat[(size_t)(brow + r)*Tx*Ux + (size_t)t*Ux + n] = (unsigned short)(dw[r] >> 16);
    }
    tgW = (tgW == 3u) ? 1u : (tgW + 1u);
  }
}

// ---------------------------------------------------------------------------
// proj_out: out[m] = feat[m][:] (bf16) . Wc (fp32) + bc
// ---------------------------------------------------------------------------
__global__ __launch_bounds__(256) void proj_out(
    const unsigned short* __restrict__ feat, const float* __restrict__ Wc,
    const float* __restrict__ bc, float* __restrict__ out)
{
  const int wv = threadIdx.x >> 6, lane = threadIdx.x & 63;
  const int m = blockIdx.x * 4 + wv;
  const unsigned short* fp = &feat[(size_t)m*1024 + lane*16];
  float s = 0.f;
  #pragma unroll
  for (int i = 0; i < 2; ++i){
    uint4 v = *(const uint4*)(fp + i*8);
    float4 w0 = *(const float4*)&Wc[lane*16 + i*8];
    float4 w1 = *(const float4*)&Wc[lane*16 + i*8 + 4];
    unsigned int vv[4] = {v.x, v.y, v.z, v.w};
    s += bf2f((unsigned short)(vv[0] & 0xFFFF))*w0.x + bf2f((unsigned short)(vv[0] >> 16))*w0.y;
    s += bf2f((unsigned short)(vv[1] & 0xFFFF))*w0.z + bf2f((unsigned short)(vv[1] >> 16))*w0.w;
    s += bf2f((unsigned short)(vv[2] & 0xFFFF))*w1.x + bf2f((unsigned short)(vv[2] >> 16))*w1.y;
    s += bf2f((unsigned short)(vv[3] & 0xFFFF))*w1.z + bf2f((unsigned short)(vv[3] >> 16))*w1.w;
  }
  for (int o = 32; o; o >>= 1) s += __shfl_down(s, o);
  if (lane == 0) out[m] = s + bc[0];
}

// ---------------------------------------------------------------------------
extern "C" void kernel_launch(void* const* d_in, const int* in_sizes, int n_in,
                              void* d_out, int out_size, void* d_ws, size_t ws_size,
                              hipStream_t stream)
{
  (void)in_sizes; (void)n_in; (void)out_size; (void)ws_size;
  const float* X  = (const float*)d_in[0];
  const float* W1 = (const float*)d_in[1];
  const float* b1 = (const float*)d_in[2];
  const float* W2 = (const float*)d_in[3];
  const float* b2 = (const float*)d_in[4];
  const float* Wc = (const float*)d_in[5];
  const float* bc = (const float*)d_in[6];
  float* out = (float*)d_out;
  char* ws = (char*)d_ws;

  unsigned short* W1T  = (unsigned short*)(ws + 0);          // 2 MiB
  unsigned short* W2T  = (unsigned short*)(ws + 2097152);    // 2 MiB
  unsigned int*   sP0  = (unsigned int*)  (ws + 4194304);    // 256 KiB packed state
  unsigned int*   sP1  = (unsigned int*)  (ws + 4456448);    // 256 KiB
  unsigned int*   flags= (unsigned int*)  (ws + 4718592);    // 1 MiB (unused in v12)
  float* hbuf          = (float*)         (ws + 5767168);    // 128 MiB
  unsigned short* feat = (unsigned short*)(ws + 5767168 + 134217728); // 64 MiB

  // zero state buffers (tag bits 0 = "invalid/initial")
  hipMemsetAsync(sP0, 0, 262144 + 262144, stream);

  prep_kernel<<<dim3(256, 2), 256, 0, stream>>>(W1, W2, W1T, W2T);
  gemm_h<<<dim3(Mx/128, Ux/128), 256, 0, stream>>>(X, W1T, b1, hbuf);

  void* args[] = { (void*)&W2T, (void*)&hbuf, (void*)&b2,
                   (void*)&sP0, (void*)&sP1, (void*)&flags, (void*)&feat };
  hipLaunchCooperativeKernel((void*)rnn_scan, dim3(128), dim3(256), args, 0, stream);

  proj_out<<<Mx/4, 256, 0, stream>>>(feat, Wc, bc, out);
}